// Round 5
// baseline (559.303 us; speedup 1.0000x reference)
//
#include <hip/hip_runtime.h>
#include <math.h>

#define Tn   400
#define Bn   2
#define Sn   96000
#define NHh  128
#define NNn  513
#define NFFT 1024
#define HOPs 256
#define PADs 512
#define TS   376      // 1 + Sn/HOPs
#define LPn  97024    // NFFT + (TS-1)*HOPs
#define CUT  21600.0f // SR*0.45
#define DPI  3.14159265358979323846

__device__ __forceinline__ float sigmoidf_(float x){ return 1.0f/(1.0f+expf(-x)); }
__device__ __forceinline__ float softplusf_(float x){ return fmaxf(x,0.0f)+log1pf(expf(-fabsf(x))); }
__device__ __forceinline__ float fsigmoid_(float x){ return __fdividef(1.0f, 1.0f + __expf(-x)); }
__device__ __forceinline__ float ftanh_(float x){
  float e = __expf(fminf(fmaxf(2.0f*x, -30.0f), 30.0f));
  return __fdividef(e - 1.0f, e + 1.0f);
}

// ---------------- setup: per-batch scalars + f64 prefix table -------------
__global__ void k_setup(const float* f0, float* fs, double* P) {
  int b = threadIdx.x;
  if (b < Bn) {
    const float* f = f0 + b*Tn;
    double sm = 0.0;
    for (int t=0;t<Tn;t++) sm += fmax((double)f[t], 20.0);
    float f0m = (float)(sm / (double)Tn);
    fs[b] = f0m;
    float midi = 69.0f + 12.0f * log2f(f0m/440.0f);
    fs[2+b] = 0.0008f * expf(-(midi-21.0f)*(1.0f/88.0f) * 2.302585093f); // b_max
    double* Pb = P + b*Tn;
    double acc = 0.0;
    for (int m=0;m<Tn;m++){ Pb[m] = acc; if (m < Tn-1) acc += (double)f[m] + (double)f[m+1]; }
    double Ctot = 120.0*((double)f[0] + Pb[Tn-1] + (double)f[Tn-1]);
    double fupmean = Ctot / (double)Sn;
    int cnt = 0;
    for (int k=1;k<=NHh;k++) if ((float)k * (float)fupmean < CUT) cnt++;
    if (cnt < 1) cnt = 1;
    fs[4+b] = (float)cnt;
  }
}

// -------- frame-rate: encode + pre MLP + gi = x@W_ih^T + b_ih -------------
__global__ void __launch_bounds__(128) k_frame1(
    const float* f0, const int* vel,
    const float* Wp1, const float* bp1,
    const float* Wp2, const float* bp2,
    const float* Wih, const float* bih,
    float* gi) {
  int bt = blockIdx.x; int b = bt / Tn, t = bt % Tn;
  __shared__ float x[72];
  __shared__ float y1[128];
  __shared__ float y2[128];
  int tid = threadIdx.x;
  if (tid < 72) {
    if (tid < 64) {
      float fv = f0[b*Tn+t];
      float fsv = fmaxf(fv, 20.0f);
      float fn = (logf(fsv) - 2.99573227355399f) * (1.0f/5.52146091786225f);
      fn = fminf(fmaxf(fn,0.0f),1.0f);
      int j = (tid>>1) + 1;
      float ang = (float)DPI * (float)j * fn;
      x[tid] = (tid & 1) ? cosf(ang) : sinf(ang);
    } else {
      int i = tid - 64;
      float vn = fminf(fmaxf((float)vel[b]*(1.0f/7.0f),0.0f),1.0f);
      int j = (i>>1)+1;
      float ang = (float)DPI * (float)j * vn;
      x[tid] = (i & 1) ? cosf(ang) : sinf(ang);
    }
  }
  __syncthreads();
  {
    float a = bp1[tid];
    #pragma unroll 8
    for (int i=0;i<72;i++) a += x[i]*Wp1[i*128+tid];
    y1[tid] = fmaxf(a,0.0f);
  }
  __syncthreads();
  {
    float a = bp2[tid];
    #pragma unroll 8
    for (int i=0;i<128;i++) a += y1[i]*Wp2[i*128+tid];
    y2[tid] = fmaxf(a,0.0f);
  }
  __syncthreads();
  float* gout = gi + ((size_t)b*Tn + t)*192;
  for (int g = tid; g < 192; g += 128) {
    float s = bih[g];
    const float* wr = Wih + g*128;
    #pragma unroll 8
    for (int d=0; d<128; d++) s += y2[d]*wr[d];
    gout[g] = s;
  }
}

// ---------------- GRU: single wave per batch, wave-synchronous ------------
// R2/R3 post-mortem: compiler REMATERIALIZED the weight loads inside the
// loop (VGPR_Count=112 < 192 needed) -> 48KB/step re-streamed from L2
// (~860 cyc/step, 243us). Fix: 192 NAMED SCALAR floats + per-iteration
// asm "+v" pins. Scalar operands avoid the gfx950 "indirect register
// inputs" error; the volatile "+v" makes each weight LOOP-CARRIED so it
// cannot be rematerialized -> must stay resident in arch VGPRs
// (192+~40 < 256 at launch_bounds(64,1)). h broadcast via v_readlane.
#define RL(x, l) __int_as_float(__builtin_amdgcn_readlane(__float_as_int(x), (l)))

#define DL16Q(g, qp, qi) \
  float g##_0,g##_1,g##_2,g##_3,g##_4,g##_5,g##_6,g##_7, \
        g##_8,g##_9,g##_10,g##_11,g##_12,g##_13,g##_14,g##_15; \
  { float4 _a=(qp)[qi], _b=(qp)[(qi)+1], _c=(qp)[(qi)+2], _d=(qp)[(qi)+3]; \
    g##_0=_a.x;  g##_1=_a.y;  g##_2=_a.z;  g##_3=_a.w; \
    g##_4=_b.x;  g##_5=_b.y;  g##_6=_b.z;  g##_7=_b.w; \
    g##_8=_c.x;  g##_9=_c.y;  g##_10=_c.z; g##_11=_c.w; \
    g##_12=_d.x; g##_13=_d.y; g##_14=_d.z; g##_15=_d.w; }

#define PIN16(g) asm volatile("" : \
  "+v"(g##_0),"+v"(g##_1),"+v"(g##_2),"+v"(g##_3), \
  "+v"(g##_4),"+v"(g##_5),"+v"(g##_6),"+v"(g##_7), \
  "+v"(g##_8),"+v"(g##_9),"+v"(g##_10),"+v"(g##_11), \
  "+v"(g##_12),"+v"(g##_13),"+v"(g##_14),"+v"(g##_15));

#define STEP16(gr, gz, gn, base) { float hb; \
  hb=RL(h,(base)+0);  ar0=fmaf(gr##_0 ,hb,ar0); az0=fmaf(gz##_0 ,hb,az0); an0=fmaf(gn##_0 ,hb,an0); \
  hb=RL(h,(base)+1);  ar1=fmaf(gr##_1 ,hb,ar1); az1=fmaf(gz##_1 ,hb,az1); an1=fmaf(gn##_1 ,hb,an1); \
  hb=RL(h,(base)+2);  ar2=fmaf(gr##_2 ,hb,ar2); az2=fmaf(gz##_2 ,hb,az2); an2=fmaf(gn##_2 ,hb,an2); \
  hb=RL(h,(base)+3);  ar3=fmaf(gr##_3 ,hb,ar3); az3=fmaf(gz##_3 ,hb,az3); an3=fmaf(gn##_3 ,hb,an3); \
  hb=RL(h,(base)+4);  ar0=fmaf(gr##_4 ,hb,ar0); az0=fmaf(gz##_4 ,hb,az0); an0=fmaf(gn##_4 ,hb,an0); \
  hb=RL(h,(base)+5);  ar1=fmaf(gr##_5 ,hb,ar1); az1=fmaf(gz##_5 ,hb,az1); an1=fmaf(gn##_5 ,hb,an1); \
  hb=RL(h,(base)+6);  ar2=fmaf(gr##_6 ,hb,ar2); az2=fmaf(gz##_6 ,hb,az2); an2=fmaf(gn##_6 ,hb,an2); \
  hb=RL(h,(base)+7);  ar3=fmaf(gr##_7 ,hb,ar3); az3=fmaf(gz##_7 ,hb,az3); an3=fmaf(gn##_7 ,hb,an3); \
  hb=RL(h,(base)+8);  ar0=fmaf(gr##_8 ,hb,ar0); az0=fmaf(gz##_8 ,hb,az0); an0=fmaf(gn##_8 ,hb,an0); \
  hb=RL(h,(base)+9);  ar1=fmaf(gr##_9 ,hb,ar1); az1=fmaf(gz##_9 ,hb,az1); an1=fmaf(gn##_9 ,hb,an1); \
  hb=RL(h,(base)+10); ar2=fmaf(gr##_10,hb,ar2); az2=fmaf(gz##_10,hb,az2); an2=fmaf(gn##_10,hb,an2); \
  hb=RL(h,(base)+11); ar3=fmaf(gr##_11,hb,ar3); az3=fmaf(gz##_11,hb,az3); an3=fmaf(gn##_11,hb,an3); \
  hb=RL(h,(base)+12); ar0=fmaf(gr##_12,hb,ar0); az0=fmaf(gz##_12,hb,az0); an0=fmaf(gn##_12,hb,an0); \
  hb=RL(h,(base)+13); ar1=fmaf(gr##_13,hb,ar1); az1=fmaf(gz##_13,hb,az1); an1=fmaf(gn##_13,hb,an1); \
  hb=RL(h,(base)+14); ar2=fmaf(gr##_14,hb,ar2); az2=fmaf(gz##_14,hb,az2); an2=fmaf(gn##_14,hb,an2); \
  hb=RL(h,(base)+15); ar3=fmaf(gr##_15,hb,ar3); az3=fmaf(gz##_15,hb,az3); an3=fmaf(gn##_15,hb,an3); }

__global__ void __launch_bounds__(64, 1) k_gru(const float* __restrict__ gi,
                                               const float* __restrict__ Whh,
                                               const float* __restrict__ bhh,
                                               float* __restrict__ hsout) {
  int b = blockIdx.x;
  int j = threadIdx.x; // 0..63
  const float4* Wr = (const float4*)(Whh + (size_t)j*64);
  const float4* Wz = (const float4*)(Whh + (size_t)(64+j)*64);
  const float4* Wn = (const float4*)(Whh + (size_t)(128+j)*64);
  DL16Q(R0, Wr, 0) DL16Q(R1, Wr, 4) DL16Q(R2, Wr, 8) DL16Q(R3, Wr, 12)
  DL16Q(Z0, Wz, 0) DL16Q(Z1, Wz, 4) DL16Q(Z2, Wz, 8) DL16Q(Z3, Wz, 12)
  DL16Q(N0, Wn, 0) DL16Q(N1, Wn, 4) DL16Q(N2, Wn, 8) DL16Q(N3, Wn, 12)
  float br = bhh[j], bz = bhh[64+j], bn = bhh[128+j];
  const float* gib = gi + (size_t)b*Tn*192;
  float* hb_ = hsout + (size_t)b*Tn*64;
  float h = 0.0f;
  // distance-2 prefetch pipeline
  float g0 = gib[j],       g1 = gib[64+j],       g2 = gib[128+j];
  float p0 = gib[192+j],   p1 = gib[192+64+j],   p2 = gib[192+128+j];
  for (int t=0;t<Tn;t++) {
    // loop-carry pins: weights must stay resident in arch VGPRs
    PIN16(R0) PIN16(R1) PIN16(R2) PIN16(R3)
    PIN16(Z0) PIN16(Z1) PIN16(Z2) PIN16(Z3)
    PIN16(N0) PIN16(N1) PIN16(N2) PIN16(N3)
    // issue loads for t+2 (consumed 2 iterations later -> latency hidden)
    int tf = (t+2 < Tn) ? t+2 : Tn-1;
    const float* gfx = gib + (size_t)tf*192;
    float f0_ = gfx[j], f1_ = gfx[64+j], f2_ = gfx[128+j];
    float ar0=0.f,ar1=0.f,ar2=0.f,ar3=0.f;
    float az0=0.f,az1=0.f,az2=0.f,az3=0.f;
    float an0=0.f,an1=0.f,an2=0.f,an3=0.f;
    STEP16(R0,Z0,N0,0)  STEP16(R1,Z1,N1,16)
    STEP16(R2,Z2,N2,32) STEP16(R3,Z3,N3,48)
    float ghr = br + ((ar0+ar1)+(ar2+ar3));
    float ghz = bz + ((az0+az1)+(az2+az3));
    float ghn = bn + ((an0+an1)+(an2+an3));
    float rg = fsigmoid_(g0 + ghr);
    float zg = fsigmoid_(g1 + ghz);
    float ng = ftanh_(g2 + rg*ghn);
    h = (1.0f - zg)*ng + zg*h;
    hb_[(size_t)t*64+j] = h;
    g0 = p0; g1 = p1; g2 = p2;
    p0 = f0_; p1 = f1_; p2 = f2_;
  }
}

// ------------- post-MLP + all heads, one block per (b,t) -----------------
__global__ void __launch_bounds__(256) k_heads(
    const float* hs, const float* Wpost, const float* bpost,
    const float* Wharm, const float* bharm,
    const float* Wamp, const float* bamp,
    const float* Wnoise, const float* bnoise,
    const float* Wnamp, const float* bnamp,
    const float* WB, const float* bB,
    float* harm, float* nmag, float* fs) {
  int bt = blockIdx.x; int b = bt / Tn, t = bt % Tn;
  __shared__ float h64[64];
  __shared__ float fp[128];
  __shared__ float lg[256];
  __shared__ float red[8]; // mx0,mx1,sum0,sum1,amp0,amp1,namp0,namp1
  int tid = threadIdx.x;
  if (tid < 64) h64[tid] = hs[((size_t)b*Tn+t)*64+tid];
  __syncthreads();
  if (tid < 128) {
    float a = bpost[tid];
    #pragma unroll 8
    for (int i=0;i<64;i++) a += h64[i]*Wpost[i*128+tid];
    fp[tid] = fmaxf(a,0.0f);
  }
  __syncthreads();
  { // harmonic logits: tid -> (c = tid>>7, n = tid&127)
    int c = tid >> 7, n = tid & 127;
    float a = bharm[c*128+n];
    const float* w = Wharm + (size_t)c*128*128 + n;
    #pragma unroll 8
    for (int d=0;d<128;d++) a += fp[d]*w[d*128];
    lg[tid] = a;
  }
  __syncthreads();
  if (tid < 2) {
    const float* l = lg + tid*128;
    float mx = l[0];
    for (int n=1;n<128;n++) mx = fmaxf(mx,l[n]);
    float sm = 0.f; for (int n=0;n<128;n++) sm += expf(l[n]-mx);
    red[tid] = mx; red[2+tid] = sm;
    float aa = bamp[tid];
    for (int d=0;d<128;d++) aa += fp[d]*Wamp[tid*128+d];
    red[4+tid] = softplusf_(aa);
    float na = bnamp[tid];
    for (int d=0;d<128;d++) na += fp[d]*Wnamp[tid*128+d];
    red[6+tid] = softplusf_(na);
  } else if (tid == 2) {
    float bb = bB[0];
    for (int d=0;d<128;d++) bb += fp[d]*WB[d];
    atomicAdd(&fs[6+b], sigmoidf_(bb));
  }
  __syncthreads();
  { // harm_amps = softmax * amp
    int c = tid >> 7, n = tid & 127;
    float v = expf(lg[tid]-red[c]) / red[2+c] * red[4+c];
    harm[(((size_t)c*Bn + b)*Tn + t)*128 + n] = v;
  }
  // noise magnitudes: 2*513 outputs
  for (int o = tid; o < 2*NNn; o += 256) {
    int c = (o < NNn) ? 0 : 1; int n = o - c*NNn;
    float a = bnoise[c*NNn+n];
    const float* w = Wnoise + (size_t)c*128*NNn + n;
    #pragma unroll 8
    for (int d=0;d<128;d++) a += fp[d]*w[(size_t)d*NNn];
    nmag[(((size_t)c*Bn + b)*Tn + t)*NNn + n] = sigmoidf_(a) * red[6+c];
  }
}

// --------- inh + per-(b,k) frequency ratios r = k*sqrt(1+inh k^2) --------
__global__ void k_inh(float* fs, double* rk) {
  int tid = threadIdx.x; // 256
  __shared__ double inh_s[2];
  if (tid < 2) {
    float inh = fs[6+tid]*(1.0f/(float)Tn) * fs[2+tid];
    fs[8+tid] = inh;
    inh_s[tid] = (double)inh;
  }
  __syncthreads();
  int b = tid >> 7, k = (tid & 127) + 1;
  double kk = (double)k;
  rk[b*128 + (k-1)] = kk * sqrt(1.0 + inh_s[b]*kk*kk);
}

// ---------------- harmonic synthesis: thread per (b,s) -------------------
__global__ void __launch_bounds__(256) k_harm(
    const float* f0, const float* harm, const double* P,
    const double* rk, const float* fs, float* sigh) {
  int b = blockIdx.y;
  int s = blockIdx.x*256 + threadIdx.x; // < 96000 exactly
  __shared__ double rks[128];
  __shared__ float  rkf[128];
  if (threadIdx.x < 128) {
    double r = rk[b*128+threadIdx.x];
    rks[threadIdx.x] = r; rkf[threadIdx.x] = (float)r;
  }
  __syncthreads();
  const float* f = f0 + b*Tn;
  float posf = ((float)s + 0.5f) * (400.0f/96000.0f) - 0.5f;
  posf = fminf(fmaxf(posf, 0.0f), 399.0f);
  int lo = (int)floorf(posf);
  int hi = min(lo+1, 399);
  float fr = posf - (float)lo;
  float f0up = f[lo]*(1.0f-fr) + f[hi]*fr;
  double C;
  if (s < 120) {
    C = (double)(s+1) * (double)f[0];
  } else if (s < 95880) {
    int m = (s-120)/240;
    int j = s - 120 - 240*m;
    double fm = (double)f[m], fm1 = (double)f[m+1];
    double jp = (double)(j+1);
    C = 120.0*((double)f[0] + P[b*Tn+m]) + jp*fm + (fm1-fm)*jp*jp*(1.0/480.0);
  } else {
    C = 120.0*((double)f[0] + P[b*Tn+399]) + (double)(s-95880+1)*(double)f[399];
  }
  double Phi = C * (2.0*DPI/48000.0);
  const float* hLlo = harm + (((size_t)0*Bn + b)*Tn + lo)*128;
  const float* hLhi = harm + (((size_t)0*Bn + b)*Tn + hi)*128;
  const float* hRlo = harm + (((size_t)1*Bn + b)*Tn + lo)*128;
  const float* hRhi = harm + (((size_t)1*Bn + b)*Tn + hi)*128;
  float accL=0.f, accR=0.f;
  for (int k=0;k<128;k++) {
    float finst = f0up * rkf[k];
    if (finst < CUT) {
      double u = rks[k]*Phi * (1.0/(2.0*DPI));
      u -= floor(u);
      float sv = __sinf((float)u * 6.28318530717959f);
      float aL = hLlo[k]*(1.0f-fr) + hLhi[k]*fr;
      float aR = hRlo[k]*(1.0f-fr) + hRhi[k]*fr;
      accL += aL*sv; accR += aR*sv;
    }
  }
  float na = fs[4+b];
  sigh[((size_t)b*2+0)*Sn + s] = accL/na;
  sigh[((size_t)b*2+1)*Sn + s] = accR/na;
}

// ------ noise: frame -> window -> FFT -> shape -> iFFT -> window -> OLA ---
__global__ void __launch_bounds__(256) k_noise(
    const float* noiseL, const float* noiseR,
    const float* nmag, const float* fs, float* ola) {
  int t = blockIdx.x;       // 0..375
  int sig = blockIdx.y;     // b*2 + c
  int b = sig >> 1, c = sig & 1;
  const float* noise = (c==0 ? noiseL : noiseR) + (size_t)b*Sn;
  __shared__ float re[1024], im[1024];
  __shared__ float twc[512], tws[512];
  __shared__ float wdw[1024];
  int tid = threadIdx.x;
  for (int j=tid; j<512; j+=256) {
    float ang = (float)(2.0*DPI) * (float)j * (1.0f/1024.0f);
    twc[j] = cosf(ang); tws[j] = sinf(ang);
  }
  for (int i=tid; i<1024; i+=256)
    wdw[i] = 0.5f - 0.5f*cosf((float)(2.0*DPI)*(float)i*(1.0f/1024.0f));
  __syncthreads();
  for (int i=tid;i<1024;i+=256) {
    int q = t*HOPs + i - PADs;
    if (q < 0) q = -q;
    if (q >= Sn) q = 2*Sn - 2 - q;
    float v = noise[q]*wdw[i];
    int br = (int)(__brev((unsigned)i) >> 22);
    re[br] = v; im[br] = 0.0f;
  }
  __syncthreads();
  for (int st=1; st<=10; st++) {
    int half = 1<<(st-1);
    #pragma unroll
    for (int w=0;w<2;w++) {
      int bid = tid + w*256;
      int pos = bid & (half-1);
      int i0 = ((bid >> (st-1)) << st) + pos;
      int i1 = i0 + half;
      int j = pos << (10-st);
      float cr = twc[j], ci = -tws[j];
      float xr = re[i1], xi = im[i1];
      float tr = cr*xr - ci*xi, ti = cr*xi + ci*xr;
      float ar = re[i0], ai = im[i0];
      re[i1] = ar - tr; im[i1] = ai - ti;
      re[i0] = ar + tr; im[i0] = ai + ti;
    }
    __syncthreads();
  }
  float f0m = fs[b];
  float pp = ((float)t + 0.5f) * (400.0f/376.0f) - 0.5f;
  pp = fminf(fmaxf(pp,0.0f),399.0f);
  int tlo = (int)floorf(pp); int thi = min(tlo+1, 399); float tfr = pp - (float)tlo;
  const float* nm = nmag + (((size_t)c*Bn + b)*Tn)*NNn;
  for (int k=tid;k<=512;k+=256) {
    float src = (float)k * 46.875f / f0m * (513.0f/128.0f);
    src = fminf(fmaxf(src,0.0f),512.0f);
    int flo = (int)src; int fhi = min(flo+1,512); float ffr = src - (float)flo;
    float vlo = nm[(size_t)tlo*NNn+flo]*(1.0f-tfr) + nm[(size_t)thi*NNn+flo]*tfr;
    float vhi = nm[(size_t)tlo*NNn+fhi]*(1.0f-tfr) + nm[(size_t)thi*NNn+fhi]*tfr;
    float mag = vlo + ffr*(vhi-vlo);
    re[k] *= mag; im[k] *= mag;
  }
  __syncthreads();
  for (int k=tid+513; k<1024; k+=256) {
    re[k] = re[1024-k]; im[k] = -im[1024-k];
  }
  __syncthreads();
  for (int i=tid;i<1024;i+=256) {
    int j = (int)(__brev((unsigned)i)>>22);
    if (i < j) {
      float a=re[i]; re[i]=re[j]; re[j]=a;
      float bb=im[i]; im[i]=im[j]; im[j]=bb;
    }
  }
  __syncthreads();
  for (int st=1; st<=10; st++) {
    int half = 1<<(st-1);
    #pragma unroll
    for (int w=0;w<2;w++) {
      int bid = tid + w*256;
      int pos = bid & (half-1);
      int i0 = ((bid >> (st-1)) << st) + pos;
      int i1 = i0 + half;
      int j = pos << (10-st);
      float cr = twc[j], ci = tws[j];
      float xr = re[i1], xi = im[i1];
      float tr = cr*xr - ci*xi, ti = cr*xi + ci*xr;
      float ar = re[i0], ai = im[i0];
      re[i1] = ar - tr; im[i1] = ai - ti;
      re[i0] = ar + tr; im[i0] = ai + ti;
    }
    __syncthreads();
  }
  float* olab = ola + (size_t)sig*LPn;
  for (int i=tid;i<1024;i+=256) {
    float y = re[i] * (1.0f/1024.0f) * wdw[i];
    atomicAdd(&olab[t*HOPs + i], y);
  }
}

// ------------- final: (harm + ola/wsq) * loudness ------------------------
__global__ void __launch_bounds__(256) k_final(
    const float* loud, const float* sigh, const float* ola, float* out) {
  int b = blockIdx.y;
  int s = blockIdx.x*256 + threadIdx.x;
  float posf = ((float)s + 0.5f)*(400.0f/96000.0f) - 0.5f;
  posf = fminf(fmaxf(posf,0.0f),399.0f);
  int lo=(int)floorf(posf); int hi=min(lo+1,399); float fr=posf-(float)lo;
  const float* ld = loud + b*Tn;
  float lv = exp10f(ld[lo]*0.05f)*(1.0f-fr) + exp10f(ld[hi]*0.05f)*fr;
  int p = PADs + s;
  int t0 = (p >= 1023) ? ((p - 1023 + 255) >> 8) : 0;
  int t1 = min(TS-1, p >> 8);
  float wsq = 0.0f;
  for (int t=t0;t<=t1;t++) {
    int i = p - (t<<8);
    float w = 0.5f - 0.5f*cosf((float)(2.0*DPI)*(float)i*(1.0f/1024.0f));
    wsq += w*w;
  }
  float denom = (wsq > 1e-11f) ? wsq : 1.0f;
  for (int c=0;c<2;c++) {
    float hv = sigh[((size_t)b*2+c)*Sn+s];
    float nv = ola[(size_t)(b*2+c)*LPn + p] / denom;
    out[((size_t)b*2+c)*Sn + s] = (hv + nv)*lv;
  }
}

extern "C" void kernel_launch(void* const* d_in, const int* in_sizes, int n_in,
                              void* d_out, int out_size, void* d_ws, size_t ws_size,
                              hipStream_t stream) {
  const float* f0    = (const float*)d_in[0];
  const float* loud  = (const float*)d_in[1];
  const float* nL    = (const float*)d_in[2];
  const float* nR    = (const float*)d_in[3];
  const float* Wp1   = (const float*)d_in[4];  const float* bp1 = (const float*)d_in[5];
  const float* Wp2   = (const float*)d_in[6];  const float* bp2 = (const float*)d_in[7];
  const float* Wih   = (const float*)d_in[8];  const float* Whh = (const float*)d_in[9];
  const float* bih   = (const float*)d_in[10]; const float* bhh = (const float*)d_in[11];
  const float* Wpost = (const float*)d_in[12]; const float* bpost=(const float*)d_in[13];
  const float* Wharm = (const float*)d_in[14]; const float* bharm=(const float*)d_in[15];
  const float* Wamp  = (const float*)d_in[16]; const float* bamp =(const float*)d_in[17];
  const float* Wnoise= (const float*)d_in[18]; const float* bnoise=(const float*)d_in[19];
  const float* Wnamp = (const float*)d_in[20]; const float* bnamp=(const float*)d_in[21];
  const float* WB    = (const float*)d_in[22]; const float* bB  = (const float*)d_in[23];
  const int*   vel   = (const int*)d_in[24];
  float* out = (float*)d_out;

  char* w = (char*)d_ws;
  double* P    = (double*)w; w += (size_t)Bn*Tn*sizeof(double);
  double* rk   = (double*)w; w += (size_t)Bn*128*sizeof(double);
  float* gi    = (float*)w;  w += (size_t)Bn*Tn*192*sizeof(float);
  float* hsb   = (float*)w;  w += (size_t)Bn*Tn*64*sizeof(float);
  float* harm  = (float*)w;  w += (size_t)2*Bn*Tn*128*sizeof(float);
  float* nmag  = (float*)w;  w += (size_t)2*Bn*Tn*NNn*sizeof(float);
  float* sigh  = (float*)w;  w += (size_t)Bn*2*Sn*sizeof(float);
  float* ola   = (float*)w;  w += (size_t)Bn*2*LPn*sizeof(float);
  float* fscal = (float*)w;  w += 32*sizeof(float);

  // ola and fscal are adjacent -> one memset covers both
  hipMemsetAsync(ola, 0, (size_t)Bn*2*LPn*sizeof(float) + 32*sizeof(float), stream);

  k_setup<<<1, 64, 0, stream>>>(f0, fscal, P);
  k_frame1<<<Bn*Tn, 128, 0, stream>>>(f0, vel, Wp1,bp1, Wp2,bp2, Wih,bih, gi);
  k_gru<<<Bn, 64, 0, stream>>>(gi, Whh, bhh, hsb);
  k_heads<<<Bn*Tn, 256, 0, stream>>>(hsb, Wpost,bpost, Wharm,bharm, Wamp,bamp,
                                     Wnoise,bnoise, Wnamp,bnamp, WB,bB,
                                     harm, nmag, fscal);
  k_inh<<<1, 256, 0, stream>>>(fscal, rk);
  dim3 gh(Sn/256, Bn);
  k_harm<<<gh, 256, 0, stream>>>(f0, harm, P, rk, fscal, sigh);
  dim3 gn(TS, Bn*2);
  k_noise<<<gn, 256, 0, stream>>>(nL, nR, nmag, fscal, ola);
  dim3 gf(Sn/256, Bn);
  k_final<<<gf, 256, 0, stream>>>(loud, sigh, ola, out);
}

// Round 6
// 463.991 us; speedup vs baseline: 1.2054x; 1.2054x over previous
//
#include <hip/hip_runtime.h>
#include <math.h>

#define Tn   400
#define Bn   2
#define Sn   96000
#define NHh  128
#define NNn  513
#define NFFT 1024
#define HOPs 256
#define PADs 512
#define TS   376      // 1 + Sn/HOPs
#define LPn  97024    // NFFT + (TS-1)*HOPs
#define CUT  21600.0f // SR*0.45
#define DPI  3.14159265358979323846

__device__ __forceinline__ float sigmoidf_(float x){ return 1.0f/(1.0f+expf(-x)); }
__device__ __forceinline__ float softplusf_(float x){ return fmaxf(x,0.0f)+log1pf(expf(-fabsf(x))); }
__device__ __forceinline__ float fsigmoid_(float x){ return __fdividef(1.0f, 1.0f + __expf(-x)); }
__device__ __forceinline__ float ftanh_(float x){
  float e = __expf(fminf(fmaxf(2.0f*x, -30.0f), 30.0f));
  return __fdividef(e - 1.0f, e + 1.0f);
}

// ---------------- setup: per-batch scalars + f64 prefix table -------------
__global__ void k_setup(const float* f0, float* fs, double* P) {
  int b = threadIdx.x;
  if (b < Bn) {
    const float* f = f0 + b*Tn;
    double sm = 0.0;
    for (int t=0;t<Tn;t++) sm += fmax((double)f[t], 20.0);
    float f0m = (float)(sm / (double)Tn);
    fs[b] = f0m;
    float midi = 69.0f + 12.0f * log2f(f0m/440.0f);
    fs[2+b] = 0.0008f * expf(-(midi-21.0f)*(1.0f/88.0f) * 2.302585093f); // b_max
    double* Pb = P + b*Tn;
    double acc = 0.0;
    for (int m=0;m<Tn;m++){ Pb[m] = acc; if (m < Tn-1) acc += (double)f[m] + (double)f[m+1]; }
    double Ctot = 120.0*((double)f[0] + Pb[Tn-1] + (double)f[Tn-1]);
    double fupmean = Ctot / (double)Sn;
    int cnt = 0;
    for (int k=1;k<=NHh;k++) if ((float)k * (float)fupmean < CUT) cnt++;
    if (cnt < 1) cnt = 1;
    fs[4+b] = (float)cnt;
  }
}

// -------- frame-rate: encode + pre MLP + gi = x@W_ih^T + b_ih -------------
__global__ void __launch_bounds__(128) k_frame1(
    const float* f0, const int* vel,
    const float* Wp1, const float* bp1,
    const float* Wp2, const float* bp2,
    const float* Wih, const float* bih,
    float* gi) {
  int bt = blockIdx.x; int b = bt / Tn, t = bt % Tn;
  __shared__ float x[72];
  __shared__ float y1[128];
  __shared__ float y2[128];
  int tid = threadIdx.x;
  if (tid < 72) {
    if (tid < 64) {
      float fv = f0[b*Tn+t];
      float fsv = fmaxf(fv, 20.0f);
      float fn = (logf(fsv) - 2.99573227355399f) * (1.0f/5.52146091786225f);
      fn = fminf(fmaxf(fn,0.0f),1.0f);
      int j = (tid>>1) + 1;
      float ang = (float)DPI * (float)j * fn;
      x[tid] = (tid & 1) ? cosf(ang) : sinf(ang);
    } else {
      int i = tid - 64;
      float vn = fminf(fmaxf((float)vel[b]*(1.0f/7.0f),0.0f),1.0f);
      int j = (i>>1)+1;
      float ang = (float)DPI * (float)j * vn;
      x[tid] = (i & 1) ? cosf(ang) : sinf(ang);
    }
  }
  __syncthreads();
  {
    float a = bp1[tid];
    #pragma unroll 8
    for (int i=0;i<72;i++) a += x[i]*Wp1[i*128+tid];
    y1[tid] = fmaxf(a,0.0f);
  }
  __syncthreads();
  {
    float a = bp2[tid];
    #pragma unroll 8
    for (int i=0;i<128;i++) a += y1[i]*Wp2[i*128+tid];
    y2[tid] = fmaxf(a,0.0f);
  }
  __syncthreads();
  float* gout = gi + ((size_t)b*Tn + t)*192;
  for (int g = tid; g < 192; g += 128) {
    float s = bih[g];
    const float* wr = Wih + g*128;
    #pragma unroll 8
    for (int d=0; d<128; d++) s += y2[d]*wr[d];
    gout[g] = s;
  }
}

// ---------------- GRU: 256 threads, role-split, LDS-only inner loop -------
// R1-R4 lesson: any design needing >~100 resident VGPRs/thread for weights
// loses to the allocator (AGPR placement / remat -> 48KB/step re-streamed
// from L2). Here thread j<192 owns ONE Whh row (64 floats = 16 float4,
// trivially resident at launch_bounds(256,1)); wave 3 owns the gates.
// Inner loop touches ONLY LDS (h broadcast + s scores), so the per-step
// barriers drain just lgkmcnt (cheap). Global traffic (gi in, h-history
// out) is chunked 8 steps deep into gate-wave registers -> one vmcnt
// drain per 8 steps instead of per step.
#define MV4(wv, xv) { a0=fmaf((wv).x,(xv).x,a0); a1=fmaf((wv).y,(xv).y,a1); \
                      a2=fmaf((wv).z,(xv).z,a2); a3=fmaf((wv).w,(xv).w,a3); }

__global__ void __launch_bounds__(256, 1) k_gru(const float* __restrict__ gi,
                                                const float* __restrict__ Whh,
                                                const float* __restrict__ bhh,
                                                float* __restrict__ hsout) {
  int b = blockIdx.x;
  int j = threadIdx.x;            // 0..255
  __shared__ float h[64];
  __shared__ float s[192];
  const float* gib = gi + (size_t)b*Tn*192;
  float* hb_ = hsout + (size_t)b*Tn*64;

  // --- matvec thread state (j<192): Whh row j in 16 named float4 regs ---
  float4 w0,w1,w2,w3,w4,w5,w6,w7,w8,w9,w10,w11,w12,w13,w14,w15;
  float bj = 0.0f;
  if (j < 192) {
    const float4* W4 = (const float4*)(Whh + (size_t)j*64);
    w0=W4[0];  w1=W4[1];  w2=W4[2];   w3=W4[3];
    w4=W4[4];  w5=W4[5];  w6=W4[6];   w7=W4[7];
    w8=W4[8];  w9=W4[9];  w10=W4[10]; w11=W4[11];
    w12=W4[12];w13=W4[13];w14=W4[14]; w15=W4[15];
    bj = bhh[j];
    if (j < 64) h[j] = 0.0f;
  }
  // --- gate thread state (j>=192, u=j-192): gi chunk + h history in regs --
  int u = j - 192;
  float hu = 0.0f;
  float ga[8], gz_[8], gn_[8], hist[8];
  if (j >= 192) {
    #pragma unroll
    for (int i=0;i<8;i++) {
      ga[i]  = gib[(size_t)i*192 + u];
      gz_[i] = gib[(size_t)i*192 + 64 + u];
      gn_[i] = gib[(size_t)i*192 + 128 + u];
    }
  }
  __syncthreads();

  for (int c=0;c<50;c++) {
    #pragma unroll
    for (int i=0;i<8;i++) {
      if (j < 192) {
        const float4* h4 = (const float4*)h;
        float4 x0=h4[0], x1=h4[1], x2=h4[2],  x3=h4[3];
        float4 x4=h4[4], x5=h4[5], x6=h4[6],  x7=h4[7];
        float4 x8=h4[8], x9=h4[9], x10=h4[10],x11=h4[11];
        float4 x12=h4[12],x13=h4[13],x14=h4[14],x15=h4[15];
        float a0=bj, a1=0.f, a2=0.f, a3=0.f;
        MV4(w0,x0)   MV4(w1,x1)   MV4(w2,x2)   MV4(w3,x3)
        MV4(w4,x4)   MV4(w5,x5)   MV4(w6,x6)   MV4(w7,x7)
        MV4(w8,x8)   MV4(w9,x9)   MV4(w10,x10) MV4(w11,x11)
        MV4(w12,x12) MV4(w13,x13) MV4(w14,x14) MV4(w15,x15)
        s[j] = ((a0+a1)+(a2+a3));
      }
      __syncthreads();   // matvec scores visible (LDS-only -> cheap drain)
      if (j >= 192) {
        float mr = s[u], mz = s[64+u], mn = s[128+u];
        float rg = fsigmoid_(ga[i]  + mr);
        float zg = fsigmoid_(gz_[i] + mz);
        float ng = ftanh_(gn_[i] + rg*mn);
        hu = (1.0f - zg)*ng + zg*hu;
        h[u] = hu;
        hist[i] = hu;
      }
      __syncthreads();   // new h visible
    }
    // chunk boundary: flush history, fetch next gi chunk (gate wave only).
    // These global ops drain ONCE at the next barrier (amortized /8 steps).
    if (j >= 192) {
      int t0 = c*8;
      #pragma unroll
      for (int i=0;i<8;i++) hb_[(size_t)(t0+i)*64 + u] = hist[i];
      if (c < 49) {
        int t1 = t0 + 8;
        #pragma unroll
        for (int i=0;i<8;i++) {
          ga[i]  = gib[(size_t)(t1+i)*192 + u];
          gz_[i] = gib[(size_t)(t1+i)*192 + 64 + u];
          gn_[i] = gib[(size_t)(t1+i)*192 + 128 + u];
        }
      }
    }
  }
}

// ------------- post-MLP + all heads, one block per (b,t) -----------------
__global__ void __launch_bounds__(256) k_heads(
    const float* hs, const float* Wpost, const float* bpost,
    const float* Wharm, const float* bharm,
    const float* Wamp, const float* bamp,
    const float* Wnoise, const float* bnoise,
    const float* Wnamp, const float* bnamp,
    const float* WB, const float* bB,
    float* harm, float* nmag, float* fs) {
  int bt = blockIdx.x; int b = bt / Tn, t = bt % Tn;
  __shared__ float h64[64];
  __shared__ float fp[128];
  __shared__ float lg[256];
  __shared__ float red[8]; // mx0,mx1,sum0,sum1,amp0,amp1,namp0,namp1
  int tid = threadIdx.x;
  if (tid < 64) h64[tid] = hs[((size_t)b*Tn+t)*64+tid];
  __syncthreads();
  if (tid < 128) {
    float a = bpost[tid];
    #pragma unroll 8
    for (int i=0;i<64;i++) a += h64[i]*Wpost[i*128+tid];
    fp[tid] = fmaxf(a,0.0f);
  }
  __syncthreads();
  { // harmonic logits: tid -> (c = tid>>7, n = tid&127)
    int c = tid >> 7, n = tid & 127;
    float a = bharm[c*128+n];
    const float* w = Wharm + (size_t)c*128*128 + n;
    #pragma unroll 8
    for (int d=0;d<128;d++) a += fp[d]*w[d*128];
    lg[tid] = a;
  }
  __syncthreads();
  if (tid < 2) {
    const float* l = lg + tid*128;
    float mx = l[0];
    for (int n=1;n<128;n++) mx = fmaxf(mx,l[n]);
    float sm = 0.f; for (int n=0;n<128;n++) sm += expf(l[n]-mx);
    red[tid] = mx; red[2+tid] = sm;
    float aa = bamp[tid];
    for (int d=0;d<128;d++) aa += fp[d]*Wamp[tid*128+d];
    red[4+tid] = softplusf_(aa);
    float na = bnamp[tid];
    for (int d=0;d<128;d++) na += fp[d]*Wnamp[tid*128+d];
    red[6+tid] = softplusf_(na);
  } else if (tid == 2) {
    float bb = bB[0];
    for (int d=0;d<128;d++) bb += fp[d]*WB[d];
    atomicAdd(&fs[6+b], sigmoidf_(bb));
  }
  __syncthreads();
  { // harm_amps = softmax * amp
    int c = tid >> 7, n = tid & 127;
    float v = expf(lg[tid]-red[c]) / red[2+c] * red[4+c];
    harm[(((size_t)c*Bn + b)*Tn + t)*128 + n] = v;
  }
  // noise magnitudes: 2*513 outputs
  for (int o = tid; o < 2*NNn; o += 256) {
    int c = (o < NNn) ? 0 : 1; int n = o - c*NNn;
    float a = bnoise[c*NNn+n];
    const float* w = Wnoise + (size_t)c*128*NNn + n;
    #pragma unroll 8
    for (int d=0;d<128;d++) a += fp[d]*w[(size_t)d*NNn];
    nmag[(((size_t)c*Bn + b)*Tn + t)*NNn + n] = sigmoidf_(a) * red[6+c];
  }
}

// --------- inh + per-(b,k) frequency ratios r = k*sqrt(1+inh k^2) --------
__global__ void k_inh(float* fs, double* rk) {
  int tid = threadIdx.x; // 256
  __shared__ double inh_s[2];
  if (tid < 2) {
    float inh = fs[6+tid]*(1.0f/(float)Tn) * fs[2+tid];
    fs[8+tid] = inh;
    inh_s[tid] = (double)inh;
  }
  __syncthreads();
  int b = tid >> 7, k = (tid & 127) + 1;
  double kk = (double)k;
  rk[b*128 + (k-1)] = kk * sqrt(1.0 + inh_s[b]*kk*kk);
}

// ---------------- harmonic synthesis: thread per (b,s) -------------------
__global__ void __launch_bounds__(256) k_harm(
    const float* f0, const float* harm, const double* P,
    const double* rk, const float* fs, float* sigh) {
  int b = blockIdx.y;
  int s = blockIdx.x*256 + threadIdx.x; // < 96000 exactly
  __shared__ double rks[128];
  __shared__ float  rkf[128];
  if (threadIdx.x < 128) {
    double r = rk[b*128+threadIdx.x];
    rks[threadIdx.x] = r; rkf[threadIdx.x] = (float)r;
  }
  __syncthreads();
  const float* f = f0 + b*Tn;
  float posf = ((float)s + 0.5f) * (400.0f/96000.0f) - 0.5f;
  posf = fminf(fmaxf(posf, 0.0f), 399.0f);
  int lo = (int)floorf(posf);
  int hi = min(lo+1, 399);
  float fr = posf - (float)lo;
  float f0up = f[lo]*(1.0f-fr) + f[hi]*fr;
  double C;
  if (s < 120) {
    C = (double)(s+1) * (double)f[0];
  } else if (s < 95880) {
    int m = (s-120)/240;
    int j = s - 120 - 240*m;
    double fm = (double)f[m], fm1 = (double)f[m+1];
    double jp = (double)(j+1);
    C = 120.0*((double)f[0] + P[b*Tn+m]) + jp*fm + (fm1-fm)*jp*jp*(1.0/480.0);
  } else {
    C = 120.0*((double)f[0] + P[b*Tn+399]) + (double)(s-95880+1)*(double)f[399];
  }
  double Phi = C * (2.0*DPI/48000.0);
  const float* hLlo = harm + (((size_t)0*Bn + b)*Tn + lo)*128;
  const float* hLhi = harm + (((size_t)0*Bn + b)*Tn + hi)*128;
  const float* hRlo = harm + (((size_t)1*Bn + b)*Tn + lo)*128;
  const float* hRhi = harm + (((size_t)1*Bn + b)*Tn + hi)*128;
  float accL=0.f, accR=0.f;
  for (int k=0;k<128;k++) {
    float finst = f0up * rkf[k];
    if (finst < CUT) {
      double u = rks[k]*Phi * (1.0/(2.0*DPI));
      u -= floor(u);
      float sv = __sinf((float)u * 6.28318530717959f);
      float aL = hLlo[k]*(1.0f-fr) + hLhi[k]*fr;
      float aR = hRlo[k]*(1.0f-fr) + hRhi[k]*fr;
      accL += aL*sv; accR += aR*sv;
    }
  }
  float na = fs[4+b];
  sigh[((size_t)b*2+0)*Sn + s] = accL/na;
  sigh[((size_t)b*2+1)*Sn + s] = accR/na;
}

// ------ noise: frame -> window -> FFT -> shape -> iFFT -> window -> OLA ---
__global__ void __launch_bounds__(256) k_noise(
    const float* noiseL, const float* noiseR,
    const float* nmag, const float* fs, float* ola) {
  int t = blockIdx.x;       // 0..375
  int sig = blockIdx.y;     // b*2 + c
  int b = sig >> 1, c = sig & 1;
  const float* noise = (c==0 ? noiseL : noiseR) + (size_t)b*Sn;
  __shared__ float re[1024], im[1024];
  __shared__ float twc[512], tws[512];
  __shared__ float wdw[1024];
  int tid = threadIdx.x;
  for (int j=tid; j<512; j+=256) {
    float ang = (float)(2.0*DPI) * (float)j * (1.0f/1024.0f);
    twc[j] = cosf(ang); tws[j] = sinf(ang);
  }
  for (int i=tid; i<1024; i+=256)
    wdw[i] = 0.5f - 0.5f*cosf((float)(2.0*DPI)*(float)i*(1.0f/1024.0f));
  __syncthreads();
  for (int i=tid;i<1024;i+=256) {
    int q = t*HOPs + i - PADs;
    if (q < 0) q = -q;
    if (q >= Sn) q = 2*Sn - 2 - q;
    float v = noise[q]*wdw[i];
    int br = (int)(__brev((unsigned)i) >> 22);
    re[br] = v; im[br] = 0.0f;
  }
  __syncthreads();
  for (int st=1; st<=10; st++) {
    int half = 1<<(st-1);
    #pragma unroll
    for (int w=0;w<2;w++) {
      int bid = tid + w*256;
      int pos = bid & (half-1);
      int i0 = ((bid >> (st-1)) << st) + pos;
      int i1 = i0 + half;
      int j = pos << (10-st);
      float cr = twc[j], ci = -tws[j];
      float xr = re[i1], xi = im[i1];
      float tr = cr*xr - ci*xi, ti = cr*xi + ci*xr;
      float ar = re[i0], ai = im[i0];
      re[i1] = ar - tr; im[i1] = ai - ti;
      re[i0] = ar + tr; im[i0] = ai + ti;
    }
    __syncthreads();
  }
  float f0m = fs[b];
  float pp = ((float)t + 0.5f) * (400.0f/376.0f) - 0.5f;
  pp = fminf(fmaxf(pp,0.0f),399.0f);
  int tlo = (int)floorf(pp); int thi = min(tlo+1, 399); float tfr = pp - (float)tlo;
  const float* nm = nmag + (((size_t)c*Bn + b)*Tn)*NNn;
  for (int k=tid;k<=512;k+=256) {
    float src = (float)k * 46.875f / f0m * (513.0f/128.0f);
    src = fminf(fmaxf(src,0.0f),512.0f);
    int flo = (int)src; int fhi = min(flo+1,512); float ffr = src - (float)flo;
    float vlo = nm[(size_t)tlo*NNn+flo]*(1.0f-tfr) + nm[(size_t)thi*NNn+flo]*tfr;
    float vhi = nm[(size_t)tlo*NNn+fhi]*(1.0f-tfr) + nm[(size_t)thi*NNn+fhi]*tfr;
    float mag = vlo + ffr*(vhi-vlo);
    re[k] *= mag; im[k] *= mag;
  }
  __syncthreads();
  for (int k=tid+513; k<1024; k+=256) {
    re[k] = re[1024-k]; im[k] = -im[1024-k];
  }
  __syncthreads();
  for (int i=tid;i<1024;i+=256) {
    int j = (int)(__brev((unsigned)i)>>22);
    if (i < j) {
      float a=re[i]; re[i]=re[j]; re[j]=a;
      float bb=im[i]; im[i]=im[j]; im[j]=bb;
    }
  }
  __syncthreads();
  for (int st=1; st<=10; st++) {
    int half = 1<<(st-1);
    #pragma unroll
    for (int w=0;w<2;w++) {
      int bid = tid + w*256;
      int pos = bid & (half-1);
      int i0 = ((bid >> (st-1)) << st) + pos;
      int i1 = i0 + half;
      int j = pos << (10-st);
      float cr = twc[j], ci = tws[j];
      float xr = re[i1], xi = im[i1];
      float tr = cr*xr - ci*xi, ti = cr*xi + ci*xr;
      float ar = re[i0], ai = im[i0];
      re[i1] = ar - tr; im[i1] = ai - ti;
      re[i0] = ar + tr; im[i0] = ai + ti;
    }
    __syncthreads();
  }
  float* olab = ola + (size_t)sig*LPn;
  for (int i=tid;i<1024;i+=256) {
    float y = re[i] * (1.0f/1024.0f) * wdw[i];
    atomicAdd(&olab[t*HOPs + i], y);
  }
}

// ------------- final: (harm + ola/wsq) * loudness ------------------------
__global__ void __launch_bounds__(256) k_final(
    const float* loud, const float* sigh, const float* ola, float* out) {
  int b = blockIdx.y;
  int s = blockIdx.x*256 + threadIdx.x;
  float posf = ((float)s + 0.5f)*(400.0f/96000.0f) - 0.5f;
  posf = fminf(fmaxf(posf,0.0f),399.0f);
  int lo=(int)floorf(posf); int hi=min(lo+1,399); float fr=posf-(float)lo;
  const float* ld = loud + b*Tn;
  float lv = exp10f(ld[lo]*0.05f)*(1.0f-fr) + exp10f(ld[hi]*0.05f)*fr;
  int p = PADs + s;
  int t0 = (p >= 1023) ? ((p - 1023 + 255) >> 8) : 0;
  int t1 = min(TS-1, p >> 8);
  float wsq = 0.0f;
  for (int t=t0;t<=t1;t++) {
    int i = p - (t<<8);
    float w = 0.5f - 0.5f*cosf((float)(2.0*DPI)*(float)i*(1.0f/1024.0f));
    wsq += w*w;
  }
  float denom = (wsq > 1e-11f) ? wsq : 1.0f;
  for (int c=0;c<2;c++) {
    float hv = sigh[((size_t)b*2+c)*Sn+s];
    float nv = ola[(size_t)(b*2+c)*LPn + p] / denom;
    out[((size_t)b*2+c)*Sn + s] = (hv + nv)*lv;
  }
}

extern "C" void kernel_launch(void* const* d_in, const int* in_sizes, int n_in,
                              void* d_out, int out_size, void* d_ws, size_t ws_size,
                              hipStream_t stream) {
  const float* f0    = (const float*)d_in[0];
  const float* loud  = (const float*)d_in[1];
  const float* nL    = (const float*)d_in[2];
  const float* nR    = (const float*)d_in[3];
  const float* Wp1   = (const float*)d_in[4];  const float* bp1 = (const float*)d_in[5];
  const float* Wp2   = (const float*)d_in[6];  const float* bp2 = (const float*)d_in[7];
  const float* Wih   = (const float*)d_in[8];  const float* Whh = (const float*)d_in[9];
  const float* bih   = (const float*)d_in[10]; const float* bhh = (const float*)d_in[11];
  const float* Wpost = (const float*)d_in[12]; const float* bpost=(const float*)d_in[13];
  const float* Wharm = (const float*)d_in[14]; const float* bharm=(const float*)d_in[15];
  const float* Wamp  = (const float*)d_in[16]; const float* bamp =(const float*)d_in[17];
  const float* Wnoise= (const float*)d_in[18]; const float* bnoise=(const float*)d_in[19];
  const float* Wnamp = (const float*)d_in[20]; const float* bnamp=(const float*)d_in[21];
  const float* WB    = (const float*)d_in[22]; const float* bB  = (const float*)d_in[23];
  const int*   vel   = (const int*)d_in[24];
  float* out = (float*)d_out;

  char* w = (char*)d_ws;
  double* P    = (double*)w; w += (size_t)Bn*Tn*sizeof(double);
  double* rk   = (double*)w; w += (size_t)Bn*128*sizeof(double);
  float* gi    = (float*)w;  w += (size_t)Bn*Tn*192*sizeof(float);
  float* hsb   = (float*)w;  w += (size_t)Bn*Tn*64*sizeof(float);
  float* harm  = (float*)w;  w += (size_t)2*Bn*Tn*128*sizeof(float);
  float* nmag  = (float*)w;  w += (size_t)2*Bn*Tn*NNn*sizeof(float);
  float* sigh  = (float*)w;  w += (size_t)Bn*2*Sn*sizeof(float);
  float* ola   = (float*)w;  w += (size_t)Bn*2*LPn*sizeof(float);
  float* fscal = (float*)w;  w += 32*sizeof(float);

  // ola and fscal are adjacent -> one memset covers both
  hipMemsetAsync(ola, 0, (size_t)Bn*2*LPn*sizeof(float) + 32*sizeof(float), stream);

  k_setup<<<1, 64, 0, stream>>>(f0, fscal, P);
  k_frame1<<<Bn*Tn, 128, 0, stream>>>(f0, vel, Wp1,bp1, Wp2,bp2, Wih,bih, gi);
  k_gru<<<Bn, 256, 0, stream>>>(gi, Whh, bhh, hsb);
  k_heads<<<Bn*Tn, 256, 0, stream>>>(hsb, Wpost,bpost, Wharm,bharm, Wamp,bamp,
                                     Wnoise,bnoise, Wnamp,bnamp, WB,bB,
                                     harm, nmag, fscal);
  k_inh<<<1, 256, 0, stream>>>(fscal, rk);
  dim3 gh(Sn/256, Bn);
  k_harm<<<gh, 256, 0, stream>>>(f0, harm, P, rk, fscal, sigh);
  dim3 gn(TS, Bn*2);
  k_noise<<<gn, 256, 0, stream>>>(nL, nR, nmag, fscal, ola);
  dim3 gf(Sn/256, Bn);
  k_final<<<gf, 256, 0, stream>>>(loud, sigh, ola, out);
}

// Round 7
// 425.589 us; speedup vs baseline: 1.3142x; 1.0902x over previous
//
#include <hip/hip_runtime.h>
#include <math.h>

#define Tn   400
#define Bn   2
#define Sn   96000
#define NHh  128
#define NNn  513
#define NFFT 1024
#define HOPs 256
#define PADs 512
#define TS   376      // 1 + Sn/HOPs
#define LPn  97024    // NFFT + (TS-1)*HOPs
#define CUT  21600.0f // SR*0.45
#define DPI  3.14159265358979323846

__device__ __forceinline__ float sigmoidf_(float x){ return 1.0f/(1.0f+expf(-x)); }
__device__ __forceinline__ float softplusf_(float x){ return fmaxf(x,0.0f)+log1pf(expf(-fabsf(x))); }
__device__ __forceinline__ float fsigmoid_(float x){ return __fdividef(1.0f, 1.0f + __expf(-x)); }
__device__ __forceinline__ float ftanh_(float x){
  float e = __expf(fminf(fmaxf(2.0f*x, -30.0f), 30.0f));
  return __fdividef(e - 1.0f, e + 1.0f);
}

// ---------------- setup: per-batch scalars + f64 prefix table -------------
__global__ void k_setup(const float* f0, float* fs, double* P) {
  int b = threadIdx.x;
  if (b < Bn) {
    const float* f = f0 + b*Tn;
    double sm = 0.0;
    for (int t=0;t<Tn;t++) sm += fmax((double)f[t], 20.0);
    float f0m = (float)(sm / (double)Tn);
    fs[b] = f0m;
    float midi = 69.0f + 12.0f * log2f(f0m/440.0f);
    fs[2+b] = 0.0008f * expf(-(midi-21.0f)*(1.0f/88.0f) * 2.302585093f); // b_max
    double* Pb = P + b*Tn;
    double acc = 0.0;
    for (int m=0;m<Tn;m++){ Pb[m] = acc; if (m < Tn-1) acc += (double)f[m] + (double)f[m+1]; }
    double Ctot = 120.0*((double)f[0] + Pb[Tn-1] + (double)f[Tn-1]);
    double fupmean = Ctot / (double)Sn;
    int cnt = 0;
    for (int k=1;k<=NHh;k++) if ((float)k * (float)fupmean < CUT) cnt++;
    if (cnt < 1) cnt = 1;
    fs[4+b] = (float)cnt;
  }
}

// -------- frame-rate: encode + pre MLP + gi = x@W_ih^T + b_ih -------------
__global__ void __launch_bounds__(128) k_frame1(
    const float* f0, const int* vel,
    const float* Wp1, const float* bp1,
    const float* Wp2, const float* bp2,
    const float* Wih, const float* bih,
    float* gi) {
  int bt = blockIdx.x; int b = bt / Tn, t = bt % Tn;
  __shared__ float x[72];
  __shared__ float y1[128];
  __shared__ float y2[128];
  int tid = threadIdx.x;
  if (tid < 72) {
    if (tid < 64) {
      float fv = f0[b*Tn+t];
      float fsv = fmaxf(fv, 20.0f);
      float fn = (logf(fsv) - 2.99573227355399f) * (1.0f/5.52146091786225f);
      fn = fminf(fmaxf(fn,0.0f),1.0f);
      int j = (tid>>1) + 1;
      float ang = (float)DPI * (float)j * fn;
      x[tid] = (tid & 1) ? cosf(ang) : sinf(ang);
    } else {
      int i = tid - 64;
      float vn = fminf(fmaxf((float)vel[b]*(1.0f/7.0f),0.0f),1.0f);
      int j = (i>>1)+1;
      float ang = (float)DPI * (float)j * vn;
      x[tid] = (i & 1) ? cosf(ang) : sinf(ang);
    }
  }
  __syncthreads();
  {
    float a = bp1[tid];
    #pragma unroll 8
    for (int i=0;i<72;i++) a += x[i]*Wp1[i*128+tid];
    y1[tid] = fmaxf(a,0.0f);
  }
  __syncthreads();
  {
    float a = bp2[tid];
    #pragma unroll 8
    for (int i=0;i<128;i++) a += y1[i]*Wp2[i*128+tid];
    y2[tid] = fmaxf(a,0.0f);
  }
  __syncthreads();
  float* gout = gi + ((size_t)b*Tn + t)*192;
  for (int g = tid; g < 192; g += 128) {
    float s = bih[g];
    const float* wr = Wih + g*128;
    #pragma unroll 8
    for (int d=0; d<128; d++) s += y2[d]*wr[d];
    gout[g] = s;
  }
}

// ------ fused GRU (blocks 0,1) + forward noise FFT (blocks 2..1505) -------
// GRU redesign after R2-R5: allocator refuses >~48 resident VGPRs across a
// barrier loop (remats weight loads -> 48KB/step L2 stream ~875cyc). Now
// thread (p=0..3, row=0..191) owns only 16 weights (4 float4 ~16 VGPRs,
// no remat incentive); partial sums via LDS; wave 12 (threads 768..831)
// computes gates. Forward FFT blocks are net-independent, so they run
// CONCURRENTLY on the other 254 CUs during the serial GRU.
__global__ void __launch_bounds__(832, 1) k_grufft(
    const float* __restrict__ gi, const float* __restrict__ Whh,
    const float* __restrict__ bhh, float* __restrict__ hsout,
    const float* __restrict__ noiseL, const float* __restrict__ noiseR,
    float2* __restrict__ spec) {
  __shared__ float h[64];
  __shared__ float sp[768];
  __shared__ float re[1024], im[1024];
  __shared__ float twc[512], tws[512];
  __shared__ float wdw[1024];
  int j = threadIdx.x;

  if (blockIdx.x >= 2) {
    // ---------------- forward FFT branch (256 working threads) ----------
    if (j >= 256) return;
    int idx = blockIdx.x - 2;
    int sig = idx / TS, t = idx % TS;
    int b = sig >> 1, c = sig & 1;
    const float* noise = (c==0 ? noiseL : noiseR) + (size_t)b*Sn;
    int tid = j;
    for (int q=tid; q<512; q+=256) {
      float ang = (float)(2.0*DPI) * (float)q * (1.0f/1024.0f);
      twc[q] = cosf(ang); tws[q] = sinf(ang);
    }
    for (int i=tid; i<1024; i+=256)
      wdw[i] = 0.5f - 0.5f*cosf((float)(2.0*DPI)*(float)i*(1.0f/1024.0f));
    __syncthreads();
    for (int i=tid;i<1024;i+=256) {
      int q = t*HOPs + i - PADs;
      if (q < 0) q = -q;
      if (q >= Sn) q = 2*Sn - 2 - q;
      float v = noise[q]*wdw[i];
      int br = (int)(__brev((unsigned)i) >> 22);
      re[br] = v; im[br] = 0.0f;
    }
    __syncthreads();
    for (int st=1; st<=10; st++) {
      int half = 1<<(st-1);
      #pragma unroll
      for (int w=0;w<2;w++) {
        int bid = tid + w*256;
        int pos = bid & (half-1);
        int i0 = ((bid >> (st-1)) << st) + pos;
        int i1 = i0 + half;
        int q = pos << (10-st);
        float cr = twc[q], ci = -tws[q];
        float xr = re[i1], xi = im[i1];
        float tr = cr*xr - ci*xi, ti = cr*xi + ci*xr;
        float ar = re[i0], ai = im[i0];
        re[i1] = ar - tr; im[i1] = ai - ti;
        re[i0] = ar + tr; im[i0] = ai + ti;
      }
      __syncthreads();
    }
    float2* so = spec + ((size_t)sig*TS + t)*NNn;
    for (int k=tid;k<=512;k+=256) so[k] = make_float2(re[k], im[k]);
    return;
  }

  // ---------------- GRU branch (832 threads, 13 waves) ------------------
  int b = blockIdx.x;
  const float* gib = gi + (size_t)b*Tn*192;
  float* hb_ = hsout + (size_t)b*Tn*64;
  int wv = j >> 6, lane = j & 63;
  // matvec thread state: 16 weights in 4 float4 (trivially VGPR-resident)
  int p = wv / 3;
  int row = (wv % 3)*64 + lane;
  float4 w0,w1,w2,w3;
  if (j < 768) {
    const float4* W4 = (const float4*)(Whh + (size_t)row*64 + p*16);
    w0=W4[0]; w1=W4[1]; w2=W4[2]; w3=W4[3];
    if (j < 64) h[j] = 0.0f;
  }
  // gate thread state (wave 12): u = lane
  int u = lane;
  float hu = 0.0f, br=0.f, bz=0.f, bn=0.f;
  float ga[8], gz_[8], gn_[8], hist[8];
  if (j >= 768) {
    br = bhh[u]; bz = bhh[64+u]; bn = bhh[128+u];
    #pragma unroll
    for (int i=0;i<8;i++) {
      ga[i]  = gib[(size_t)i*192 + u];
      gz_[i] = gib[(size_t)i*192 + 64 + u];
      gn_[i] = gib[(size_t)i*192 + 128 + u];
    }
  }
  __syncthreads();

  for (int c=0;c<50;c++) {
    #pragma unroll
    for (int i=0;i<8;i++) {
      if (j < 768) {
        const float4* h4 = (const float4*)h;
        float4 x0=h4[p*4+0], x1=h4[p*4+1], x2=h4[p*4+2], x3=h4[p*4+3];
        float a0,a1,a2,a3;
        a0 = w0.x*x0.x; a1 = w0.y*x0.y; a2 = w0.z*x0.z; a3 = w0.w*x0.w;
        a0 = fmaf(w1.x,x1.x,a0); a1 = fmaf(w1.y,x1.y,a1);
        a2 = fmaf(w1.z,x1.z,a2); a3 = fmaf(w1.w,x1.w,a3);
        a0 = fmaf(w2.x,x2.x,a0); a1 = fmaf(w2.y,x2.y,a1);
        a2 = fmaf(w2.z,x2.z,a2); a3 = fmaf(w2.w,x2.w,a3);
        a0 = fmaf(w3.x,x3.x,a0); a1 = fmaf(w3.y,x3.y,a1);
        a2 = fmaf(w3.z,x3.z,a2); a3 = fmaf(w3.w,x3.w,a3);
        sp[p*192 + row] = (a0+a1)+(a2+a3);
      }
      __syncthreads();   // partials visible (LDS-only drain)
      if (j >= 768) {
        float mr = (sp[u]      + sp[192+u])     + (sp[384+u]     + sp[576+u]);
        float mz = (sp[64+u]   + sp[192+64+u])  + (sp[384+64+u]  + sp[576+64+u]);
        float mn = (sp[128+u]  + sp[192+128+u]) + (sp[384+128+u] + sp[576+128+u]);
        float rg = fsigmoid_(ga[i]  + br + mr);
        float zg = fsigmoid_(gz_[i] + bz + mz);
        float ng = ftanh_(gn_[i] + rg*(bn + mn));
        hu = (1.0f - zg)*ng + zg*hu;
        h[u] = hu;
        hist[i] = hu;
      }
      __syncthreads();   // new h visible
    }
    // chunk boundary: flush history, fetch next gi chunk (gate wave only);
    // one vmcnt drain per 8 steps instead of per step.
    if (j >= 768) {
      int t0 = c*8;
      #pragma unroll
      for (int i=0;i<8;i++) hb_[(size_t)(t0+i)*64 + u] = hist[i];
      if (c < 49) {
        int t1 = t0 + 8;
        #pragma unroll
        for (int i=0;i<8;i++) {
          ga[i]  = gib[(size_t)(t1+i)*192 + u];
          gz_[i] = gib[(size_t)(t1+i)*192 + 64 + u];
          gn_[i] = gib[(size_t)(t1+i)*192 + 128 + u];
        }
      }
    }
  }
}

// ------------- post-MLP + all heads, one block per (b,t) -----------------
__global__ void __launch_bounds__(256) k_heads(
    const float* hs, const float* Wpost, const float* bpost,
    const float* Wharm, const float* bharm,
    const float* Wamp, const float* bamp,
    const float* Wnoise, const float* bnoise,
    const float* Wnamp, const float* bnamp,
    const float* WB, const float* bB,
    float* harm, float* nmag, float* fs) {
  int bt = blockIdx.x; int b = bt / Tn, t = bt % Tn;
  __shared__ float h64[64];
  __shared__ float fp[128];
  __shared__ float lg[256];
  __shared__ float red[8]; // mx0,mx1,sum0,sum1,amp0,amp1,namp0,namp1
  int tid = threadIdx.x;
  if (tid < 64) h64[tid] = hs[((size_t)b*Tn+t)*64+tid];
  __syncthreads();
  if (tid < 128) {
    float a = bpost[tid];
    #pragma unroll 8
    for (int i=0;i<64;i++) a += h64[i]*Wpost[i*128+tid];
    fp[tid] = fmaxf(a,0.0f);
  }
  __syncthreads();
  { // harmonic logits: tid -> (c = tid>>7, n = tid&127)
    int c = tid >> 7, n = tid & 127;
    float a = bharm[c*128+n];
    const float* w = Wharm + (size_t)c*128*128 + n;
    #pragma unroll 8
    for (int d=0;d<128;d++) a += fp[d]*w[d*128];
    lg[tid] = a;
  }
  __syncthreads();
  if (tid < 2) {
    const float* l = lg + tid*128;
    float mx = l[0];
    for (int n=1;n<128;n++) mx = fmaxf(mx,l[n]);
    float sm = 0.f; for (int n=0;n<128;n++) sm += expf(l[n]-mx);
    red[tid] = mx; red[2+tid] = sm;
    float aa = bamp[tid];
    for (int d=0;d<128;d++) aa += fp[d]*Wamp[tid*128+d];
    red[4+tid] = softplusf_(aa);
    float na = bnamp[tid];
    for (int d=0;d<128;d++) na += fp[d]*Wnamp[tid*128+d];
    red[6+tid] = softplusf_(na);
  } else if (tid == 2) {
    float bb = bB[0];
    for (int d=0;d<128;d++) bb += fp[d]*WB[d];
    atomicAdd(&fs[6+b], sigmoidf_(bb));
  }
  __syncthreads();
  { // harm_amps = softmax * amp
    int c = tid >> 7, n = tid & 127;
    float v = expf(lg[tid]-red[c]) / red[2+c] * red[4+c];
    harm[(((size_t)c*Bn + b)*Tn + t)*128 + n] = v;
  }
  // noise magnitudes: 2*513 outputs
  for (int o = tid; o < 2*NNn; o += 256) {
    int c = (o < NNn) ? 0 : 1; int n = o - c*NNn;
    float a = bnoise[c*NNn+n];
    const float* w = Wnoise + (size_t)c*128*NNn + n;
    #pragma unroll 8
    for (int d=0;d<128;d++) a += fp[d]*w[(size_t)d*NNn];
    nmag[(((size_t)c*Bn + b)*Tn + t)*NNn + n] = sigmoidf_(a) * red[6+c];
  }
}

// --------- inh + per-(b,k) frequency ratios r = k*sqrt(1+inh k^2) --------
__global__ void k_inh(float* fs, double* rk) {
  int tid = threadIdx.x; // 256
  __shared__ double inh_s[2];
  if (tid < 2) {
    float inh = fs[6+tid]*(1.0f/(float)Tn) * fs[2+tid];
    fs[8+tid] = inh;
    inh_s[tid] = (double)inh;
  }
  __syncthreads();
  int b = tid >> 7, k = (tid & 127) + 1;
  double kk = (double)k;
  rk[b*128 + (k-1)] = kk * sqrt(1.0 + inh_s[b]*kk*kk);
}

// ---------------- harmonic synthesis: thread per (b,s) -------------------
__global__ void __launch_bounds__(256) k_harm(
    const float* f0, const float* harm, const double* P,
    const double* rk, const float* fs, float* sigh) {
  int b = blockIdx.y;
  int s = blockIdx.x*256 + threadIdx.x; // < 96000 exactly
  __shared__ double rks[128];
  __shared__ float  rkf[128];
  if (threadIdx.x < 128) {
    double r = rk[b*128+threadIdx.x];
    rks[threadIdx.x] = r; rkf[threadIdx.x] = (float)r;
  }
  __syncthreads();
  const float* f = f0 + b*Tn;
  float posf = ((float)s + 0.5f) * (400.0f/96000.0f) - 0.5f;
  posf = fminf(fmaxf(posf, 0.0f), 399.0f);
  int lo = (int)floorf(posf);
  int hi = min(lo+1, 399);
  float fr = posf - (float)lo;
  float f0up = f[lo]*(1.0f-fr) + f[hi]*fr;
  double C;
  if (s < 120) {
    C = (double)(s+1) * (double)f[0];
  } else if (s < 95880) {
    int m = (s-120)/240;
    int j = s - 120 - 240*m;
    double fm = (double)f[m], fm1 = (double)f[m+1];
    double jp = (double)(j+1);
    C = 120.0*((double)f[0] + P[b*Tn+m]) + jp*fm + (fm1-fm)*jp*jp*(1.0/480.0);
  } else {
    C = 120.0*((double)f[0] + P[b*Tn+399]) + (double)(s-95880+1)*(double)f[399];
  }
  double Phi = C * (2.0*DPI/48000.0);
  const float* hLlo = harm + (((size_t)0*Bn + b)*Tn + lo)*128;
  const float* hLhi = harm + (((size_t)0*Bn + b)*Tn + hi)*128;
  const float* hRlo = harm + (((size_t)1*Bn + b)*Tn + lo)*128;
  const float* hRhi = harm + (((size_t)1*Bn + b)*Tn + hi)*128;
  float accL=0.f, accR=0.f;
  for (int k=0;k<128;k++) {
    float finst = f0up * rkf[k];
    if (finst < CUT) {
      double u = rks[k]*Phi * (1.0/(2.0*DPI));
      u -= floor(u);
      float sv = __sinf((float)u * 6.28318530717959f);
      float aL = hLlo[k]*(1.0f-fr) + hLhi[k]*fr;
      float aR = hRlo[k]*(1.0f-fr) + hRhi[k]*fr;
      accL += aL*sv; accR += aR*sv;
    }
  }
  float na = fs[4+b];
  sigh[((size_t)b*2+0)*Sn + s] = accL/na;
  sigh[((size_t)b*2+1)*Sn + s] = accR/na;
}

// ------ noise path 2: load spec -> shape -> iFFT -> window -> OLA --------
__global__ void __launch_bounds__(256) k_noise2(
    const float2* __restrict__ spec,
    const float* nmag, const float* fs, float* ola) {
  int t = blockIdx.x;       // 0..375
  int sig = blockIdx.y;     // b*2 + c
  int b = sig >> 1, c = sig & 1;
  __shared__ float re[1024], im[1024];
  __shared__ float twc[512], tws[512];
  __shared__ float wdw[1024];
  int tid = threadIdx.x;
  for (int q=tid; q<512; q+=256) {
    float ang = (float)(2.0*DPI) * (float)q * (1.0f/1024.0f);
    twc[q] = cosf(ang); tws[q] = sinf(ang);
  }
  for (int i=tid; i<1024; i+=256)
    wdw[i] = 0.5f - 0.5f*cosf((float)(2.0*DPI)*(float)i*(1.0f/1024.0f));
  // shape bins 0..512 with freq-warped, time-interped noise mags
  float f0m = fs[b];
  float pp = ((float)t + 0.5f) * (400.0f/376.0f) - 0.5f;
  pp = fminf(fmaxf(pp,0.0f),399.0f);
  int tlo = (int)floorf(pp); int thi = min(tlo+1, 399); float tfr = pp - (float)tlo;
  const float* nm = nmag + (((size_t)c*Bn + b)*Tn)*NNn;
  const float2* so = spec + ((size_t)sig*TS + t)*NNn;
  for (int k=tid;k<=512;k+=256) {
    float src = (float)k * 46.875f / f0m * (513.0f/128.0f);
    src = fminf(fmaxf(src,0.0f),512.0f);
    int flo = (int)src; int fhi = min(flo+1,512); float ffr = src - (float)flo;
    float vlo = nm[(size_t)tlo*NNn+flo]*(1.0f-tfr) + nm[(size_t)thi*NNn+flo]*tfr;
    float vhi = nm[(size_t)tlo*NNn+fhi]*(1.0f-tfr) + nm[(size_t)thi*NNn+fhi]*tfr;
    float mag = vlo + ffr*(vhi-vlo);
    float2 v = so[k];
    re[k] = v.x*mag; im[k] = v.y*mag;
  }
  __syncthreads();
  // Hermitian mirror for bins 513..1023
  for (int k=tid+513; k<1024; k+=256) {
    re[k] = re[1024-k]; im[k] = -im[1024-k];
  }
  __syncthreads();
  // bit-reverse permute (involution; pair owned by smaller index)
  for (int i=tid;i<1024;i+=256) {
    int jx = (int)(__brev((unsigned)i)>>22);
    if (i < jx) {
      float a=re[i]; re[i]=re[jx]; re[jx]=a;
      float bb=im[i]; im[i]=im[jx]; im[jx]=bb;
    }
  }
  __syncthreads();
  // inverse FFT (e^{+i theta})
  for (int st=1; st<=10; st++) {
    int half = 1<<(st-1);
    #pragma unroll
    for (int w=0;w<2;w++) {
      int bid = tid + w*256;
      int pos = bid & (half-1);
      int i0 = ((bid >> (st-1)) << st) + pos;
      int i1 = i0 + half;
      int q = pos << (10-st);
      float cr = twc[q], ci = tws[q];
      float xr = re[i1], xi = im[i1];
      float tr = cr*xr - ci*xi, ti = cr*xi + ci*xr;
      float ar = re[i0], ai = im[i0];
      re[i1] = ar - tr; im[i1] = ai - ti;
      re[i0] = ar + tr; im[i0] = ai + ti;
    }
    __syncthreads();
  }
  float* olab = ola + (size_t)sig*LPn;
  for (int i=tid;i<1024;i+=256) {
    float y = re[i] * (1.0f/1024.0f) * wdw[i];
    atomicAdd(&olab[t*HOPs + i], y);
  }
}

// ------ noise path B (fallback, full fwd+inv in one kernel) ---------------
__global__ void __launch_bounds__(256) k_noiseB(
    const float* noiseL, const float* noiseR,
    const float* nmag, const float* fs, float* ola) {
  int t = blockIdx.x;
  int sig = blockIdx.y;
  int b = sig >> 1, c = sig & 1;
  const float* noise = (c==0 ? noiseL : noiseR) + (size_t)b*Sn;
  __shared__ float re[1024], im[1024];
  __shared__ float twc[512], tws[512];
  __shared__ float wdw[1024];
  int tid = threadIdx.x;
  for (int q=tid; q<512; q+=256) {
    float ang = (float)(2.0*DPI) * (float)q * (1.0f/1024.0f);
    twc[q] = cosf(ang); tws[q] = sinf(ang);
  }
  for (int i=tid; i<1024; i+=256)
    wdw[i] = 0.5f - 0.5f*cosf((float)(2.0*DPI)*(float)i*(1.0f/1024.0f));
  __syncthreads();
  for (int i=tid;i<1024;i+=256) {
    int q = t*HOPs + i - PADs;
    if (q < 0) q = -q;
    if (q >= Sn) q = 2*Sn - 2 - q;
    float v = noise[q]*wdw[i];
    int br = (int)(__brev((unsigned)i) >> 22);
    re[br] = v; im[br] = 0.0f;
  }
  __syncthreads();
  for (int st=1; st<=10; st++) {
    int half = 1<<(st-1);
    #pragma unroll
    for (int w=0;w<2;w++) {
      int bid = tid + w*256;
      int pos = bid & (half-1);
      int i0 = ((bid >> (st-1)) << st) + pos;
      int i1 = i0 + half;
      int q = pos << (10-st);
      float cr = twc[q], ci = -tws[q];
      float xr = re[i1], xi = im[i1];
      float tr = cr*xr - ci*xi, ti = cr*xi + ci*xr;
      float ar = re[i0], ai = im[i0];
      re[i1] = ar - tr; im[i1] = ai - ti;
      re[i0] = ar + tr; im[i0] = ai + ti;
    }
    __syncthreads();
  }
  float f0m = fs[b];
  float pp = ((float)t + 0.5f) * (400.0f/376.0f) - 0.5f;
  pp = fminf(fmaxf(pp,0.0f),399.0f);
  int tlo = (int)floorf(pp); int thi = min(tlo+1, 399); float tfr = pp - (float)tlo;
  const float* nm = nmag + (((size_t)c*Bn + b)*Tn)*NNn;
  for (int k=tid;k<=512;k+=256) {
    float src = (float)k * 46.875f / f0m * (513.0f/128.0f);
    src = fminf(fmaxf(src,0.0f),512.0f);
    int flo = (int)src; int fhi = min(flo+1,512); float ffr = src - (float)flo;
    float vlo = nm[(size_t)tlo*NNn+flo]*(1.0f-tfr) + nm[(size_t)thi*NNn+flo]*tfr;
    float vhi = nm[(size_t)tlo*NNn+fhi]*(1.0f-tfr) + nm[(size_t)thi*NNn+fhi]*tfr;
    float mag = vlo + ffr*(vhi-vlo);
    re[k] *= mag; im[k] *= mag;
  }
  __syncthreads();
  for (int k=tid+513; k<1024; k+=256) {
    re[k] = re[1024-k]; im[k] = -im[1024-k];
  }
  __syncthreads();
  for (int i=tid;i<1024;i+=256) {
    int jx = (int)(__brev((unsigned)i)>>22);
    if (i < jx) {
      float a=re[i]; re[i]=re[jx]; re[jx]=a;
      float bb=im[i]; im[i]=im[jx]; im[jx]=bb;
    }
  }
  __syncthreads();
  for (int st=1; st<=10; st++) {
    int half = 1<<(st-1);
    #pragma unroll
    for (int w=0;w<2;w++) {
      int bid = tid + w*256;
      int pos = bid & (half-1);
      int i0 = ((bid >> (st-1)) << st) + pos;
      int i1 = i0 + half;
      int q = pos << (10-st);
      float cr = twc[q], ci = tws[q];
      float xr = re[i1], xi = im[i1];
      float tr = cr*xr - ci*xi, ti = cr*xi + ci*xr;
      float ar = re[i0], ai = im[i0];
      re[i1] = ar - tr; im[i1] = ai - ti;
      re[i0] = ar + tr; im[i0] = ai + ti;
    }
    __syncthreads();
  }
  float* olab = ola + (size_t)sig*LPn;
  for (int i=tid;i<1024;i+=256) {
    float y = re[i] * (1.0f/1024.0f) * wdw[i];
    atomicAdd(&olab[t*HOPs + i], y);
  }
}

// ------------- final: (harm + ola/wsq) * loudness ------------------------
__global__ void __launch_bounds__(256) k_final(
    const float* loud, const float* sigh, const float* ola, float* out) {
  int b = blockIdx.y;
  int s = blockIdx.x*256 + threadIdx.x;
  float posf = ((float)s + 0.5f)*(400.0f/96000.0f) - 0.5f;
  posf = fminf(fmaxf(posf,0.0f),399.0f);
  int lo=(int)floorf(posf); int hi=min(lo+1,399); float fr=posf-(float)lo;
  const float* ld = loud + b*Tn;
  float lv = exp10f(ld[lo]*0.05f)*(1.0f-fr) + exp10f(ld[hi]*0.05f)*fr;
  int p = PADs + s;
  int t0 = (p >= 1023) ? ((p - 1023 + 255) >> 8) : 0;
  int t1 = min(TS-1, p >> 8);
  float wsq = 0.0f;
  for (int t=t0;t<=t1;t++) {
    int i = p - (t<<8);
    float w = 0.5f - 0.5f*cosf((float)(2.0*DPI)*(float)i*(1.0f/1024.0f));
    wsq += w*w;
  }
  float denom = (wsq > 1e-11f) ? wsq : 1.0f;
  for (int c=0;c<2;c++) {
    float hv = sigh[((size_t)b*2+c)*Sn+s];
    float nv = ola[(size_t)(b*2+c)*LPn + p] / denom;
    out[((size_t)b*2+c)*Sn + s] = (hv + nv)*lv;
  }
}

extern "C" void kernel_launch(void* const* d_in, const int* in_sizes, int n_in,
                              void* d_out, int out_size, void* d_ws, size_t ws_size,
                              hipStream_t stream) {
  const float* f0    = (const float*)d_in[0];
  const float* loud  = (const float*)d_in[1];
  const float* nL    = (const float*)d_in[2];
  const float* nR    = (const float*)d_in[3];
  const float* Wp1   = (const float*)d_in[4];  const float* bp1 = (const float*)d_in[5];
  const float* Wp2   = (const float*)d_in[6];  const float* bp2 = (const float*)d_in[7];
  const float* Wih   = (const float*)d_in[8];  const float* Whh = (const float*)d_in[9];
  const float* bih   = (const float*)d_in[10]; const float* bhh = (const float*)d_in[11];
  const float* Wpost = (const float*)d_in[12]; const float* bpost=(const float*)d_in[13];
  const float* Wharm = (const float*)d_in[14]; const float* bharm=(const float*)d_in[15];
  const float* Wamp  = (const float*)d_in[16]; const float* bamp =(const float*)d_in[17];
  const float* Wnoise= (const float*)d_in[18]; const float* bnoise=(const float*)d_in[19];
  const float* Wnamp = (const float*)d_in[20]; const float* bnamp=(const float*)d_in[21];
  const float* WB    = (const float*)d_in[22]; const float* bB  = (const float*)d_in[23];
  const int*   vel   = (const int*)d_in[24];
  float* out = (float*)d_out;

  char* w = (char*)d_ws;
  double* P    = (double*)w; w += (size_t)Bn*Tn*sizeof(double);
  double* rk   = (double*)w; w += (size_t)Bn*128*sizeof(double);
  float* gi    = (float*)w;  w += (size_t)Bn*Tn*192*sizeof(float);
  float* hsb   = (float*)w;  w += (size_t)Bn*Tn*64*sizeof(float);
  float* harm  = (float*)w;  w += (size_t)2*Bn*Tn*128*sizeof(float);
  float* nmag  = (float*)w;  w += (size_t)2*Bn*Tn*NNn*sizeof(float);
  float* sigh  = (float*)w;  w += (size_t)Bn*2*Sn*sizeof(float);
  float* ola   = (float*)w;  w += (size_t)Bn*2*LPn*sizeof(float);
  float* fscal = (float*)w;  w += 32*sizeof(float);
  float2* spec = (float2*)w; w += (size_t)4*TS*NNn*sizeof(float2);
  // fused path needs the spec buffer; deterministic per-session -> capture-safe
  bool fused = ((size_t)(w - (char*)d_ws) <= ws_size);

  // ola and fscal are adjacent -> one memset covers both
  hipMemsetAsync(ola, 0, (size_t)Bn*2*LPn*sizeof(float) + 32*sizeof(float), stream);

  k_setup<<<1, 64, 0, stream>>>(f0, fscal, P);
  k_frame1<<<Bn*Tn, 128, 0, stream>>>(f0, vel, Wp1,bp1, Wp2,bp2, Wih,bih, gi);
  if (fused) {
    k_grufft<<<2 + 4*TS, 832, 0, stream>>>(gi, Whh, bhh, hsb, nL, nR, spec);
  } else {
    k_grufft<<<2, 832, 0, stream>>>(gi, Whh, bhh, hsb, nL, nR, (float2*)ola);
  }
  k_heads<<<Bn*Tn, 256, 0, stream>>>(hsb, Wpost,bpost, Wharm,bharm, Wamp,bamp,
                                     Wnoise,bnoise, Wnamp,bnamp, WB,bB,
                                     harm, nmag, fscal);
  k_inh<<<1, 256, 0, stream>>>(fscal, rk);
  dim3 gh(Sn/256, Bn);
  k_harm<<<gh, 256, 0, stream>>>(f0, harm, P, rk, fscal, sigh);
  dim3 gn(TS, Bn*2);
  if (fused) {
    k_noise2<<<gn, 256, 0, stream>>>(spec, nmag, fscal, ola);
  } else {
    k_noiseB<<<gn, 256, 0, stream>>>(nL, nR, nmag, fscal, ola);
  }
  dim3 gf(Sn/256, Bn);
  k_final<<<gf, 256, 0, stream>>>(loud, sigh, ola, out);
}